// Round 6
// baseline (1757.929 us; speedup 1.0000x reference)
//
#include <hip/hip_runtime.h>

typedef _Float16 half8 __attribute__((ext_vector_type(8)));
typedef float floatx4 __attribute__((ext_vector_type(4)));

#define DEV_INLINE __device__ __forceinline__

constexpr int D0 = 512, D1 = 256, D2 = 256, D3 = 128;
constexpr int NROWS = 16384;
constexpr int MBLK = 32;            // batch rows per block (2 blocks/CU)
constexpr int NBLK = NROWS / MBLK;  // 512 blocks = 2x CU count
constexpr int KITERS = 16;
constexpr float ETA = 0.1f;

// packed-weight element offsets (fp16 elements) inside d_ws
constexpr int OFF_WF0 = 0;                  // fwd W0: K=256, N=512
constexpr int OFF_WF1 = OFF_WF0 + D1 * D0;  // fwd W1: K=256, N=256
constexpr int OFF_WF2 = OFF_WF1 + D2 * D1;  // fwd W2: K=128, N=256
constexpr int OFF_WB0 = OFF_WF2 + D3 * D2;  // bwd W0^T: K=512, N=256
constexpr int OFF_WB1 = OFF_WB0 + D0 * D1;  // bwd W1^T: K=256, N=256
constexpr int OFF_WB2 = OFF_WB1 + D1 * D2;  // bwd W2^T: K=256, N=128
constexpr int PACK_ELEMS = OFF_WB2 + D2 * D3;  // 458752 elems = 896 KB fp16

// ---------------------------------------------------------------------------
// Repack weights into MFMA B-fragment order + cast x0 to fp16 (if ws fits).
// B-frag layout (16x16x32): lane l supplies B[kt*32 + (l>>4)*8 + j][nt*16 + (l&15)],
// j=0..7 contiguous -> pack index ((kt*NT + nt)*64 + l)*8 + j.
// ---------------------------------------------------------------------------
__global__ void repack_kernel(const float* __restrict__ W0, const float* __restrict__ W1,
                              const float* __restrict__ W2, const float* __restrict__ x0,
                              _Float16* __restrict__ pack, _Float16* __restrict__ x0h,
                              int do_x0) {
  int p = blockIdx.x * 256 + threadIdx.x;
  if (p < PACK_ELEMS) {
    const float* W; int Csrc, Nd, off; bool tr;
    if (p < OFF_WF1)      { W = W0; Csrc = D0; Nd = D0; off = OFF_WF0; tr = false; }
    else if (p < OFF_WF2) { W = W1; Csrc = D1; Nd = D1; off = OFF_WF1; tr = false; }
    else if (p < OFF_WB0) { W = W2; Csrc = D2; Nd = D2; off = OFF_WF2; tr = false; }
    else if (p < OFF_WB1) { W = W0; Csrc = D0; Nd = D1; off = OFF_WB0; tr = true;  }
    else if (p < OFF_WB2) { W = W1; Csrc = D1; Nd = D1; off = OFF_WB1; tr = true;  }
    else                  { W = W2; Csrc = D2; Nd = D3; off = OFF_WB2; tr = true;  }
    int local = p - off;
    int j  = local & 7;
    int l  = (local >> 3) & 63;
    int fr = local >> 9;
    int NT = Nd >> 4;
    int nt = fr % NT, kt = fr / NT;
    int k = kt * 32 + ((l >> 4) << 3) + j;
    int n = nt * 16 + (l & 15);
    float v = tr ? W[n * Csrc + k] : W[k * Csrc + n];
    pack[p] = (_Float16)v;
  } else if (do_x0) {
    int q = p - PACK_ELEMS;
    if (q < NROWS * D0) x0h[q] = (_Float16)x0[q];
  }
}

DEV_INLINE float fast_tanh(float x) {
  float e = __expf(2.f * x);                       // v_exp_f32
  return 1.f - 2.f * __builtin_amdgcn_rcpf(e + 1.f);
}

// ---------------------------------------------------------------------------
// Tiled matmul: acc[rt*AS+ct] += A(RT*16 x KSTEPS*32) @ Bpack[ntBase..+CT).
// B-fragments flow through a depth-P register pipeline (compile-time indices
// only). A in LDS, fp16, row stride STRB bytes, XOR-swizzled by ((row&7)<<4).
// ---------------------------------------------------------------------------
template <int RT, int KSTEPS, int NTT, int CT, int AS, int STRB, int P>
DEV_INLINE void mm_tiles(const char* __restrict__ A, const _Float16* __restrict__ Bp,
                         int ntBase, int lane, floatx4* acc) {
  const int arow = lane & 15;
  const int aoff = (lane >> 4) << 4;  // byte offset of this lane's 16B k-chunk
  const _Float16* bbase = Bp + ((size_t)(ntBase)*64 + lane) * 8;
  half8 bq[P][CT];
#pragma unroll
  for (int s = 0; s < P; ++s)
    if (s < KSTEPS)
#pragma unroll
      for (int ct = 0; ct < CT; ++ct)
        bq[s][ct] = *(const half8*)(bbase + (s * NTT + ct) * 512);
#pragma unroll
  for (int k0 = 0; k0 < KSTEPS; ++k0) {
    half8 a[RT];
#pragma unroll
    for (int rt = 0; rt < RT; ++rt) {
      int row = rt * 16 + arow;
      int byte = (row * STRB + k0 * 64 + aoff) ^ ((row & 7) << 4);
      a[rt] = *(const half8*)(A + byte);
    }
#pragma unroll
    for (int ct = 0; ct < CT; ++ct)
#pragma unroll
      for (int rt = 0; rt < RT; ++rt)
        acc[rt * AS + ct] =
            __builtin_amdgcn_mfma_f32_16x16x32_f16(a[rt], bq[k0 % P][ct], acc[rt * AS + ct], 0, 0, 0);
    if (k0 + P < KSTEPS)
#pragma unroll
      for (int ct = 0; ct < CT; ++ct)
        bq[k0 % P][ct] = *(const half8*)(bbase + ((k0 + P) * NTT + ct) * 512);
  }
}

// ---------------------------------------------------------------------------
// Persistent settling kernel, MBLK=32 rows/block, 256 threads (4 waves),
// 80 KB LDS -> 2 independent blocks per CU (decoupled barriers = cross-block
// latency hiding; round-5 showed 1 block/CU lockstep leaves 90% idle).
// States live as fp16 in LDS; x3 keeps fp32 register master. LDS (80 KB):
//   AX1 [16K]: x1 [32][256] s512    AG0 [16K]: g0-half [32][256] s512
//   AQ  [16K]: x2 [32][256] s512    AG1 [16K]: g1 [32][256] s512
//   AR  [16K]: x3 [32][128] s256  aliased with  g2 [32][256] s512
// Per iter: ph1(+ep->AG1), {ph3h(+ep->AG0), B, ph4h, B} x2, ph4ep->AX1,
//           ph2, B, ep->AR, ph5, B, ep->AQ, ph6, B, ep->AR.
// Every C-cell is owned by exactly one thread, so epilogue RMW of the fp16
// state via ds_read_u16/ds_write_u16 is race-free.
// ---------------------------------------------------------------------------
__global__ __launch_bounds__(256)
__attribute__((amdgpu_waves_per_eu(2, 2)))
void settle_kernel(const float* __restrict__ x0,
                   const _Float16* __restrict__ x0h,
                   const _Float16* __restrict__ pack,
                   float* __restrict__ out) {
  extern __shared__ char lds[];
  char* AX1 = lds;
  char* AG0 = lds + 16384;
  char* AQ  = lds + 32768;
  char* AG1 = lds + 49152;
  char* AR  = lds + 65536;

  const int tid  = threadIdx.x;
  const int lane = tid & 63;
  const int wave = tid >> 6;          // 0..3
  const int row0 = blockIdx.x * MBLK;
  const int rsub = (lane >> 4) << 2;  // C/D layout: row = (lane>>4)*4 + i
  const int csub = lane & 15;         //             col = lane & 15

  // zero-init x2 (AQ, 16K) and x3 image (AR, first 8K)
  {
    floatx4 z = {0.f, 0.f, 0.f, 0.f};
    for (int i = tid; i < 1024; i += 256) ((floatx4*)AQ)[i] = z;
    for (int i = tid; i < 512; i += 256) ((floatx4*)AR)[i] = z;
  }

  const floatx4 zf = {0.f, 0.f, 0.f, 0.f};
  floatx4 x3m[4];  // [rt*2+ct], cols (wave*2+ct)*16+csub
#pragma unroll
  for (int i = 0; i < 4; ++i) x3m[i] = zf;

  const _Float16* Wf0 = pack + OFF_WF0;
  const _Float16* Wf1 = pack + OFF_WF1;
  const _Float16* Wf2 = pack + OFF_WF2;
  const _Float16* Wb0 = pack + OFF_WB0;
  const _Float16* Wb1 = pack + OFF_WB1;
  const _Float16* Wb2 = pack + OFF_WB2;

  // =================== iteration 0 shortcut ===================
  // all states zero: g0 = x0 (f'(0)=1); only dx1 = x0 @ W0^T is nonzero.
  {
    floatx4 dx1a[8];
#pragma unroll
    for (int i = 0; i < 8; ++i) dx1a[i] = zf;
    for (int h = 0; h < 2; ++h) {
      for (int idx = tid; idx < MBLK * 256; idx += 256) {
        int row = idx >> 8, colh = idx & 255;
        size_t gi = (size_t)(row0 + row) * D0 + h * 256 + colh;
        _Float16 v = x0h ? x0h[gi] : (_Float16)x0[gi];
        int byte = (row * 512 + colh * 2) ^ ((row & 7) << 4);
        *(_Float16*)(AG0 + byte) = v;
      }
      __syncthreads();  // publish g0 half
#pragma unroll
      for (int p = 0; p < 2; ++p)
        mm_tiles<2, 8, 16, 2, 4, 512, 2>(AG0, Wb0 + h * 65536, wave * 4 + p * 2, lane,
                                         &dx1a[p * 2]);
      __syncthreads();  // reads done -> AG0 reusable
    }
#pragma unroll
    for (int rt = 0; rt < 2; ++rt)
#pragma unroll
      for (int c = 0; c < 4; ++c) {
        int col = (wave * 4 + c) * 16 + csub;
#pragma unroll
        for (int i = 0; i < 4; ++i) {
          int row = rt * 16 + rsub + i;
          float dx = fminf(1.f, fmaxf(-1.f, dx1a[rt * 4 + c][i]));
          int byte = (row * 512 + col * 2) ^ ((row & 7) << 4);
          *(_Float16*)(AX1 + byte) = (_Float16)(ETA * dx);
        }
      }
    __syncthreads();  // publish x1
  }

  // =================== iterations 1..15 ===================
  for (int it = 1; it < KITERS; ++it) {
    floatx4 dx1a[8];
    // ---- ph1: preact1 = x2 @ W1 (reads AQ); ep: e1, g1 -> AG1, dx1a = -e1
    {
#pragma unroll
      for (int i = 0; i < 8; ++i) dx1a[i] = zf;
#pragma unroll
      for (int p = 0; p < 2; ++p)
        mm_tiles<2, 8, 16, 2, 4, 512, 2>(AQ, Wf1, wave * 4 + p * 2, lane, &dx1a[p * 2]);
#pragma unroll
      for (int rt = 0; rt < 2; ++rt)
#pragma unroll
        for (int c = 0; c < 4; ++c) {
          int col = (wave * 4 + c) * 16 + csub;
#pragma unroll
          for (int i = 0; i < 4; ++i) {
            int row = rt * 16 + rsub + i;
            int sb = (row * 512 + col * 2) ^ ((row & 7) << 4);
            float t = fast_tanh(dx1a[rt * 4 + c][i]);
            float x1o = (float)*(const _Float16*)(AX1 + sb);
            float e = x1o - t;
            *(_Float16*)(AG1 + sb) = (_Float16)(e * (1.f - t * t));
            dx1a[rt * 4 + c][i] = -e;
          }
        }
    }
    // ---- ph3/ph4 interleaved over the two K/N=256 halves of g0
    for (int h = 0; h < 2; ++h) {
      // ph3 half: preact0 cols h*256..; g0h -> AG0 (two CT=2 passes)
#pragma unroll
      for (int p = 0; p < 2; ++p) {
        floatx4 acc4[4];
#pragma unroll
        for (int i = 0; i < 4; ++i) acc4[i] = zf;
        mm_tiles<2, 8, 32, 2, 2, 512, 2>(AX1, Wf0, h * 16 + wave * 4 + p * 2, lane, acc4);
#pragma unroll
        for (int rt = 0; rt < 2; ++rt)
#pragma unroll
          for (int ct = 0; ct < 2; ++ct) {
            int colh = (wave * 4 + p * 2 + ct) * 16 + csub;
#pragma unroll
            for (int i = 0; i < 4; ++i) {
              int row = rt * 16 + rsub + i;
              float t = fast_tanh(acc4[rt * 2 + ct][i]);
              size_t gi = (size_t)(row0 + row) * D0 + h * 256 + colh;
              float xv = x0h ? (float)x0h[gi] : x0[gi];
              float g = (xv - t) * (1.f - t * t);
              int byte = (row * 512 + colh * 2) ^ ((row & 7) << 4);
              *(_Float16*)(AG0 + byte) = (_Float16)g;
            }
          }
      }
      __syncthreads();  // g0h published
#pragma unroll
      for (int p = 0; p < 2; ++p)
        mm_tiles<2, 8, 16, 2, 4, 512, 2>(AG0, Wb0 + h * 65536, wave * 4 + p * 2, lane,
                                         &dx1a[p * 2]);
      __syncthreads();  // ph4 half reads done -> AG0 reusable / AX1 writable
    }
    // ---- ph4 epilogue: x1 += eta*clip(dx1a)  (RMW own cells of AX1)
#pragma unroll
    for (int rt = 0; rt < 2; ++rt)
#pragma unroll
      for (int c = 0; c < 4; ++c) {
        int col = (wave * 4 + c) * 16 + csub;
#pragma unroll
        for (int i = 0; i < 4; ++i) {
          int row = rt * 16 + rsub + i;
          int sb = (row * 512 + col * 2) ^ ((row & 7) << 4);
          float dx = fminf(1.f, fmaxf(-1.f, dx1a[rt * 4 + c][i]));
          float x1o = (float)*(const _Float16*)(AX1 + sb);
          *(_Float16*)(AX1 + sb) = (_Float16)(x1o + ETA * dx);
        }
      }
    // ---- ph2: preact2 = x3 @ W2 (reads AR x3 image); B; ep: e2, g2 -> AR
    floatx4 dx2a[8];
    {
#pragma unroll
      for (int i = 0; i < 8; ++i) dx2a[i] = zf;
#pragma unroll
      for (int p = 0; p < 2; ++p)
        mm_tiles<2, 4, 16, 2, 4, 256, 2>(AR, Wf2, wave * 4 + p * 2, lane, &dx2a[p * 2]);
      __syncthreads();  // all x3-image reads done before g2 overwrites AR
#pragma unroll
      for (int rt = 0; rt < 2; ++rt)
#pragma unroll
        for (int c = 0; c < 4; ++c) {
          int col = (wave * 4 + c) * 16 + csub;
#pragma unroll
          for (int i = 0; i < 4; ++i) {
            int row = rt * 16 + rsub + i;
            int sb = (row * 512 + col * 2) ^ ((row & 7) << 4);
            float t = fast_tanh(dx2a[rt * 4 + c][i]);
            float x2o = (float)*(const _Float16*)(AQ + sb);
            float e = x2o - t;
            *(_Float16*)(AR + sb) = (_Float16)(e * (1.f - t * t));
            dx2a[rt * 4 + c][i] = -e;
          }
        }
    }
    // ---- ph5: dx2a += g1 @ W1^T (reads AG1); B; ep: x2 RMW in AQ
    {
#pragma unroll
      for (int p = 0; p < 2; ++p)
        mm_tiles<2, 8, 16, 2, 4, 512, 2>(AG1, Wb1, wave * 4 + p * 2, lane, &dx2a[p * 2]);
      __syncthreads();  // covers ep2 AQ reads vs writes below; AG1 reads done
#pragma unroll
      for (int rt = 0; rt < 2; ++rt)
#pragma unroll
        for (int c = 0; c < 4; ++c) {
          int col = (wave * 4 + c) * 16 + csub;
#pragma unroll
          for (int i = 0; i < 4; ++i) {
            int row = rt * 16 + rsub + i;
            int sb = (row * 512 + col * 2) ^ ((row & 7) << 4);
            float dx = fminf(1.f, fmaxf(-1.f, dx2a[rt * 4 + c][i]));
            float x2o = (float)*(const _Float16*)(AQ + sb);
            *(_Float16*)(AQ + sb) = (_Float16)(x2o + ETA * dx);
          }
        }
    }
    // ---- ph6: dx3 = g2 @ W2^T (reads AR g2); B; ep: x3m +=; x3 image -> AR
    {
      floatx4 acc6[4];
#pragma unroll
      for (int i = 0; i < 4; ++i) acc6[i] = zf;
      mm_tiles<2, 8, 8, 2, 2, 512, 2>(AR, Wb2, wave * 2, lane, acc6);
      __syncthreads();  // all g2 reads done before x3 image overwrites AR
#pragma unroll
      for (int rt = 0; rt < 2; ++rt)
#pragma unroll
        for (int ct = 0; ct < 2; ++ct) {
          int col = (wave * 2 + ct) * 16 + csub;
#pragma unroll
          for (int i = 0; i < 4; ++i) {
            int row = rt * 16 + rsub + i;
            float dx = fminf(1.f, fmaxf(-1.f, acc6[rt * 2 + ct][i]));
            float nv = x3m[rt * 2 + ct][i] + ETA * dx;
            x3m[rt * 2 + ct][i] = nv;
            int byte = (row * 256 + col * 2) ^ ((row & 7) << 4);
            *(_Float16*)(AR + byte) = (_Float16)nv;
          }
        }
    }
  }

  // write settled x3 (fp32 master)
#pragma unroll
  for (int rt = 0; rt < 2; ++rt)
#pragma unroll
    for (int ct = 0; ct < 2; ++ct) {
      int col = (wave * 2 + ct) * 16 + csub;
#pragma unroll
      for (int i = 0; i < 4; ++i) {
        int row = rt * 16 + rsub + i;
        out[(size_t)(row0 + row) * D3 + col] = x3m[rt * 2 + ct][i];
      }
    }
}

extern "C" void kernel_launch(void* const* d_in, const int* in_sizes, int n_in,
                              void* d_out, int out_size, void* d_ws, size_t ws_size,
                              hipStream_t stream) {
  const float* x0 = (const float*)d_in[0];
  const float* W0 = (const float*)d_in[1];
  const float* W1 = (const float*)d_in[2];
  const float* W2 = (const float*)d_in[3];
  float* out = (float*)d_out;

  _Float16* pack = (_Float16*)d_ws;
  const size_t pack_bytes = (size_t)PACK_ELEMS * 2;
  const size_t x0h_bytes = (size_t)NROWS * D0 * 2;
  int do_x0 = (ws_size >= pack_bytes + x0h_bytes) ? 1 : 0;
  _Float16* x0h = do_x0 ? (_Float16*)((char*)d_ws + pack_bytes) : nullptr;

  int total = PACK_ELEMS + (do_x0 ? NROWS * D0 : 0);
  repack_kernel<<<(total + 255) / 256, 256, 0, stream>>>(W0, W1, W2, x0, pack, x0h, do_x0);

  (void)hipFuncSetAttribute(reinterpret_cast<const void*>(settle_kernel),
                            hipFuncAttributeMaxDynamicSharedMemorySize, 81920);
  settle_kernel<<<NBLK, 256, 81920, stream>>>(x0, x0h, pack, out);
}

// Round 7
// 1632.751 us; speedup vs baseline: 1.0767x; 1.0767x over previous
//
#include <hip/hip_runtime.h>

typedef _Float16 half8 __attribute__((ext_vector_type(8)));
typedef float floatx4 __attribute__((ext_vector_type(4)));

#define DEV_INLINE __device__ __forceinline__

constexpr int D0 = 512, D1 = 256, D2 = 256, D3 = 128;
constexpr int NROWS = 16384;
constexpr int MBLK = 64;            // batch rows per block
constexpr int NBLK = NROWS / MBLK;  // 256 blocks == #CUs
constexpr int KITERS = 16;
constexpr float ETA = 0.1f;

// packed-weight element offsets (fp16 elements) inside d_ws
constexpr int OFF_WF0 = 0;                  // fwd W0: K=256, N=512
constexpr int OFF_WF1 = OFF_WF0 + D1 * D0;  // fwd W1: K=256, N=256
constexpr int OFF_WF2 = OFF_WF1 + D2 * D1;  // fwd W2: K=128, N=256
constexpr int OFF_WB0 = OFF_WF2 + D3 * D2;  // bwd W0^T: K=512, N=256
constexpr int OFF_WB1 = OFF_WB0 + D0 * D1;  // bwd W1^T: K=256, N=256
constexpr int OFF_WB2 = OFF_WB1 + D1 * D2;  // bwd W2^T: K=256, N=128
constexpr int PACK_ELEMS = OFF_WB2 + D2 * D3;  // 458752 elems = 896 KB fp16

// ---------------------------------------------------------------------------
// Repack weights into MFMA B-fragment order.
// B-frag layout (16x16x32): lane l supplies B[kt*32 + (l>>4)*8 + j][nt*16 + (l&15)],
// j=0..7 contiguous -> pack index ((kt*NT + nt)*64 + l)*8 + j.
// ---------------------------------------------------------------------------
__global__ void repack_kernel(const float* __restrict__ W0, const float* __restrict__ W1,
                              const float* __restrict__ W2, _Float16* __restrict__ pack) {
  int p = blockIdx.x * 256 + threadIdx.x;
  if (p >= PACK_ELEMS) return;
  const float* W; int Csrc, Nd, off; bool tr;
  if (p < OFF_WF1)      { W = W0; Csrc = D0; Nd = D0; off = OFF_WF0; tr = false; }
  else if (p < OFF_WF2) { W = W1; Csrc = D1; Nd = D1; off = OFF_WF1; tr = false; }
  else if (p < OFF_WB0) { W = W2; Csrc = D2; Nd = D2; off = OFF_WF2; tr = false; }
  else if (p < OFF_WB1) { W = W0; Csrc = D0; Nd = D1; off = OFF_WB0; tr = true;  }
  else if (p < OFF_WB2) { W = W1; Csrc = D1; Nd = D1; off = OFF_WB1; tr = true;  }
  else                  { W = W2; Csrc = D2; Nd = D3; off = OFF_WB2; tr = true;  }
  int local = p - off;
  int j  = local & 7;
  int l  = (local >> 3) & 63;
  int fr = local >> 9;
  int NT = Nd >> 4;
  int nt = fr % NT, kt = fr / NT;
  int k = kt * 32 + ((l >> 4) << 3) + j;
  int n = nt * 16 + (l & 15);
  float v = tr ? W[n * Csrc + k] : W[k * Csrc + n];
  pack[p] = (_Float16)v;
}

DEV_INLINE float fast_tanh(float x) {
  float e = __expf(2.f * x);                       // v_exp_f32
  return 1.f - 2.f * __builtin_amdgcn_rcpf(e + 1.f);
}

// ---------------------------------------------------------------------------
// Tiled matmul: acc(4 x CT tiles) += A(64 x KSTEPS*32) @ Bpack[ntBase..+CT).
// B-fragments flow through a depth-P register pipeline (compile-time indices
// only -> registers, no scratch). A in LDS, fp16, row stride STRB bytes,
// XOR-swizzled by ((row&7)<<4).
// ---------------------------------------------------------------------------
template <int KSTEPS, int NTT, int CT, int STRB, int P>
DEV_INLINE void mm_tiles(const char* __restrict__ A, const _Float16* __restrict__ Bp,
                         int ntBase, int lane, floatx4* acc) {
  const int arow = lane & 15;
  const int aoff = (lane >> 4) << 4;  // byte offset of this lane's 16B k-chunk
  const _Float16* bbase = Bp + ((size_t)(ntBase)*64 + lane) * 8;
  half8 bq[P][CT];
#pragma unroll
  for (int s = 0; s < P; ++s)
    if (s < KSTEPS)
#pragma unroll
      for (int ct = 0; ct < CT; ++ct)
        bq[s][ct] = *(const half8*)(bbase + (s * NTT + ct) * 512);
#pragma unroll
  for (int k0 = 0; k0 < KSTEPS; ++k0) {
    half8 a[4];
#pragma unroll
    for (int rt = 0; rt < 4; ++rt) {
      int row = rt * 16 + arow;
      int byte = (row * STRB + k0 * 64 + aoff) ^ ((row & 7) << 4);
      a[rt] = *(const half8*)(A + byte);
    }
#pragma unroll
    for (int ct = 0; ct < CT; ++ct)
#pragma unroll
      for (int rt = 0; rt < 4; ++rt)
        acc[rt * CT + ct] =
            __builtin_amdgcn_mfma_f32_16x16x32_f16(a[rt], bq[k0 % P][ct], acc[rt * CT + ct], 0, 0, 0);
    if (k0 + P < KSTEPS)
#pragma unroll
      for (int ct = 0; ct < CT; ++ct)
        bq[k0 % P][ct] = *(const half8*)(bbase + ((k0 + P) * NTT + ct) * 512);
  }
}

// ---------------------------------------------------------------------------
// Persistent settling kernel. States live as fp16 in LDS (no fp32 register
// masters except x3 = output); x0 tile lives in registers (x0r). LDS (160 KB):
//   AX1 [32K]: x1  [64][256] s512   AG0 [32K]: g0-half [64][256] s512
//   AQ  [32K]: x2  [64][256] s512   AG1 [32K]: g1 [64][256] s512
//   AR  [32K]: x3 [64][128] s256  aliased with  g2 [64][256] s512
// Per iter: ph1(+ep->AG1), {ph3h(+ep->AG0), B, ph4h, B} x2, ph4ep->AX1,
//           ph2, B, ep->AR, ph5, B, ep->AQ, ph6, B, ep->AR.
// Every C-cell is owned by exactly one thread, so epilogue RMW of the fp16
// state via ds_read_u16/ds_write_u16 is race-free.
// __launch_bounds__(512, 2): canonical HIP spelling for min 2 waves/EU ->
// 256-VGPR allocator budget (LDS already caps us at 1 block/CU = 2 waves/SIMD;
// rounds 1-6 were pinned at 128 VGPR and spilled).
// ---------------------------------------------------------------------------
__global__ __launch_bounds__(512, 2)
void settle_kernel(const float* __restrict__ x0,
                   const _Float16* __restrict__ pack,
                   float* __restrict__ out) {
  extern __shared__ char lds[];
  char* AX1 = lds;
  char* AG0 = lds + 32768;
  char* AQ  = lds + 65536;
  char* AG1 = lds + 98304;
  char* AR  = lds + 131072;

  const int tid  = threadIdx.x;
  const int lane = tid & 63;
  const int wave = tid >> 6;
  const int row0 = blockIdx.x * MBLK;
  const int rsub = (lane >> 4) << 2;  // C/D layout: row = (lane>>4)*4 + i
  const int csub = lane & 15;         //             col = lane & 15

  // ---- preload this block's x0 tile into registers (fp16), C-cell ownership
  // layout: li = ((h*2 + c)*4 + rt)*4 + i  <->  row = rt*16+rsub+i,
  //         col = h*256 + (wave*2+c)*16 + csub
  half8 x0r[8];
#pragma unroll
  for (int h = 0; h < 2; ++h)
#pragma unroll
    for (int c = 0; c < 2; ++c)
#pragma unroll
      for (int rt = 0; rt < 4; ++rt)
#pragma unroll
        for (int i = 0; i < 4; ++i) {
          int row = rt * 16 + rsub + i;
          int col = h * 256 + (wave * 2 + c) * 16 + csub;
          float v = x0[(size_t)(row0 + row) * D0 + col];
          int li = ((h * 2 + c) * 4 + rt) * 4 + i;
          x0r[li >> 3][li & 7] = (_Float16)v;
        }

  // zero-init x2 (AQ, 32K) and x3 image (AR, first 16K)
  {
    floatx4 z = {0.f, 0.f, 0.f, 0.f};
    for (int i = tid; i < 2048; i += 512) ((floatx4*)AQ)[i] = z;
    for (int i = tid; i < 1024; i += 512) ((floatx4*)AR)[i] = z;
  }

  const floatx4 zf = {0.f, 0.f, 0.f, 0.f};
  floatx4 x3m[4];
#pragma unroll
  for (int i = 0; i < 4; ++i) x3m[i] = zf;

  const _Float16* Wf0 = pack + OFF_WF0;
  const _Float16* Wf1 = pack + OFF_WF1;
  const _Float16* Wf2 = pack + OFF_WF2;
  const _Float16* Wb0 = pack + OFF_WB0;
  const _Float16* Wb1 = pack + OFF_WB1;
  const _Float16* Wb2 = pack + OFF_WB2;

  // =================== iteration 0 shortcut ===================
  // all states zero: g0 = x0 (f'(0)=1); only dx1 = x0 @ W0^T is nonzero.
  {
    floatx4 dx1a[8];
#pragma unroll
    for (int i = 0; i < 8; ++i) dx1a[i] = zf;
#pragma unroll
    for (int h = 0; h < 2; ++h) {
      // stage g0-half = x0-half from registers
#pragma unroll
      for (int c = 0; c < 2; ++c)
#pragma unroll
        for (int rt = 0; rt < 4; ++rt)
#pragma unroll
          for (int i = 0; i < 4; ++i) {
            int row = rt * 16 + rsub + i;
            int colh = (wave * 2 + c) * 16 + csub;
            int li = ((h * 2 + c) * 4 + rt) * 4 + i;
            int byte = (row * 512 + colh * 2) ^ ((row & 7) << 4);
            *(_Float16*)(AG0 + byte) = x0r[li >> 3][li & 7];
          }
      __syncthreads();  // publish g0 half
      mm_tiles<8, 16, 2, 512, 4>(AG0, Wb0 + h * 65536, wave * 2, lane, dx1a);
      __syncthreads();  // reads done -> AG0 reusable
    }
#pragma unroll
    for (int rt = 0; rt < 4; ++rt)
#pragma unroll
      for (int ct = 0; ct < 2; ++ct) {
        int col = (wave * 2 + ct) * 16 + csub;
#pragma unroll
        for (int i = 0; i < 4; ++i) {
          int row = rt * 16 + rsub + i;
          float dx = fminf(1.f, fmaxf(-1.f, dx1a[rt * 2 + ct][i]));
          int byte = (row * 512 + col * 2) ^ ((row & 7) << 4);
          *(_Float16*)(AX1 + byte) = (_Float16)(ETA * dx);
        }
      }
    __syncthreads();  // publish x1
  }

  // =================== iterations 1..15 ===================
  for (int it = 1; it < KITERS; ++it) {
    floatx4 dx1a[8];
    // ---- ph1: preact1 = x2 @ W1 (reads AQ); ep: e1, g1 -> AG1, dx1a = -e1
    {
#pragma unroll
      for (int i = 0; i < 8; ++i) dx1a[i] = zf;
      mm_tiles<8, 16, 2, 512, 4>(AQ, Wf1, wave * 2, lane, dx1a);
#pragma unroll
      for (int rt = 0; rt < 4; ++rt)
#pragma unroll
        for (int ct = 0; ct < 2; ++ct) {
          int col = (wave * 2 + ct) * 16 + csub;
#pragma unroll
          for (int i = 0; i < 4; ++i) {
            int row = rt * 16 + rsub + i;
            int sb = (row * 512 + col * 2) ^ ((row & 7) << 4);
            float t = fast_tanh(dx1a[rt * 2 + ct][i]);
            float x1o = (float)*(const _Float16*)(AX1 + sb);
            float e = x1o - t;
            *(_Float16*)(AG1 + sb) = (_Float16)(e * (1.f - t * t));
            dx1a[rt * 2 + ct][i] = -e;
          }
        }
    }
    // ---- ph3/ph4 interleaved over the two K/N=256 halves of g0
#pragma unroll
    for (int h = 0; h < 2; ++h) {
      // ph3 half: preact0 cols h*256.. ; g0h -> AG0 (one CT=2 pass)
      {
        floatx4 acc4[8];
#pragma unroll
        for (int i = 0; i < 8; ++i) acc4[i] = zf;
        mm_tiles<8, 32, 2, 512, 4>(AX1, Wf0, h * 16 + wave * 2, lane, acc4);
#pragma unroll
        for (int ct = 0; ct < 2; ++ct) {
          int colh = (wave * 2 + ct) * 16 + csub;
#pragma unroll
          for (int rt = 0; rt < 4; ++rt)
#pragma unroll
            for (int i = 0; i < 4; ++i) {
              int row = rt * 16 + rsub + i;
              int li = ((h * 2 + ct) * 4 + rt) * 4 + i;
              float t = fast_tanh(acc4[rt * 2 + ct][i]);
              float xv = (float)x0r[li >> 3][li & 7];
              float g = (xv - t) * (1.f - t * t);
              int byte = (row * 512 + colh * 2) ^ ((row & 7) << 4);
              *(_Float16*)(AG0 + byte) = (_Float16)g;
            }
        }
      }
      __syncthreads();  // g0h published
      mm_tiles<8, 16, 2, 512, 4>(AG0, Wb0 + h * 65536, wave * 2, lane, dx1a);
      __syncthreads();  // ph4 half reads done -> AG0 reusable / AX1 writable
    }
    // ---- ph4 epilogue: x1 += eta*clip(dx1a)  (RMW own cells of AX1)
#pragma unroll
    for (int rt = 0; rt < 4; ++rt)
#pragma unroll
      for (int ct = 0; ct < 2; ++ct) {
        int col = (wave * 2 + ct) * 16 + csub;
#pragma unroll
        for (int i = 0; i < 4; ++i) {
          int row = rt * 16 + rsub + i;
          int sb = (row * 512 + col * 2) ^ ((row & 7) << 4);
          float dx = fminf(1.f, fmaxf(-1.f, dx1a[rt * 2 + ct][i]));
          float x1o = (float)*(const _Float16*)(AX1 + sb);
          *(_Float16*)(AX1 + sb) = (_Float16)(x1o + ETA * dx);
        }
      }
    // ---- ph2: preact2 = x3 @ W2 (reads AR x3 image); B; ep: e2, g2 -> AR
    floatx4 dx2a[8];
    {
#pragma unroll
      for (int i = 0; i < 8; ++i) dx2a[i] = zf;
      mm_tiles<4, 16, 2, 256, 4>(AR, Wf2, wave * 2, lane, dx2a);
      __syncthreads();  // all x3-image reads done before g2 overwrites AR
#pragma unroll
      for (int rt = 0; rt < 4; ++rt)
#pragma unroll
        for (int ct = 0; ct < 2; ++ct) {
          int col = (wave * 2 + ct) * 16 + csub;
#pragma unroll
          for (int i = 0; i < 4; ++i) {
            int row = rt * 16 + rsub + i;
            int sb = (row * 512 + col * 2) ^ ((row & 7) << 4);
            float t = fast_tanh(dx2a[rt * 2 + ct][i]);
            float x2o = (float)*(const _Float16*)(AQ + sb);
            float e = x2o - t;
            *(_Float16*)(AR + sb) = (_Float16)(e * (1.f - t * t));
            dx2a[rt * 2 + ct][i] = -e;
          }
        }
    }
    // ---- ph5: dx2a += g1 @ W1^T (reads AG1); B; ep: x2 RMW in AQ
    {
      mm_tiles<8, 16, 2, 512, 4>(AG1, Wb1, wave * 2, lane, dx2a);
      __syncthreads();  // covers ph2-ep AQ reads vs writes below; AG1 reads done
#pragma unroll
      for (int rt = 0; rt < 4; ++rt)
#pragma unroll
        for (int ct = 0; ct < 2; ++ct) {
          int col = (wave * 2 + ct) * 16 + csub;
#pragma unroll
          for (int i = 0; i < 4; ++i) {
            int row = rt * 16 + rsub + i;
            int sb = (row * 512 + col * 2) ^ ((row & 7) << 4);
            float dx = fminf(1.f, fmaxf(-1.f, dx2a[rt * 2 + ct][i]));
            float x2o = (float)*(const _Float16*)(AQ + sb);
            *(_Float16*)(AQ + sb) = (_Float16)(x2o + ETA * dx);
          }
        }
    }
    // ---- ph6: dx3 = g2 @ W2^T (reads AR g2); B; ep: x3m += ; x3 image -> AR
    {
      floatx4 acc6[4];
#pragma unroll
      for (int i = 0; i < 4; ++i) acc6[i] = zf;
      mm_tiles<8, 8, 1, 512, 4>(AR, Wb2, wave, lane, acc6);
      __syncthreads();  // all g2 reads done before x3 image overwrites AR
      int col = wave * 16 + csub;
#pragma unroll
      for (int rt = 0; rt < 4; ++rt)
#pragma unroll
        for (int i = 0; i < 4; ++i) {
          int row = rt * 16 + rsub + i;
          float dx = fminf(1.f, fmaxf(-1.f, acc6[rt][i]));
          float nv = x3m[rt][i] + ETA * dx;
          x3m[rt][i] = nv;
          int byte = (row * 256 + col * 2) ^ ((row & 7) << 4);
          *(_Float16*)(AR + byte) = (_Float16)nv;
        }
    }
  }

  // write settled x3 (fp32 master)
  {
    int col = wave * 16 + csub;
#pragma unroll
    for (int rt = 0; rt < 4; ++rt)
#pragma unroll
      for (int i = 0; i < 4; ++i) {
        int row = rt * 16 + rsub + i;
        out[(size_t)(row0 + row) * D3 + col] = x3m[rt][i];
      }
  }
}

extern "C" void kernel_launch(void* const* d_in, const int* in_sizes, int n_in,
                              void* d_out, int out_size, void* d_ws, size_t ws_size,
                              hipStream_t stream) {
  const float* x0 = (const float*)d_in[0];
  const float* W0 = (const float*)d_in[1];
  const float* W1 = (const float*)d_in[2];
  const float* W2 = (const float*)d_in[3];
  float* out = (float*)d_out;

  _Float16* pack = (_Float16*)d_ws;
  repack_kernel<<<(PACK_ELEMS + 255) / 256, 256, 0, stream>>>(W0, W1, W2, pack);

  (void)hipFuncSetAttribute(reinterpret_cast<const void*>(settle_kernel),
                            hipFuncAttributeMaxDynamicSharedMemorySize, 163840);
  settle_kernel<<<NBLK, 512, 163840, stream>>>(x0, pack, out);
}

// Round 8
// 1573.694 us; speedup vs baseline: 1.1171x; 1.0375x over previous
//
#include <hip/hip_runtime.h>

typedef _Float16 half8 __attribute__((ext_vector_type(8)));
typedef float floatx4 __attribute__((ext_vector_type(4)));

#define DEV_INLINE __device__ __forceinline__

constexpr int D0 = 512, D1 = 256, D2 = 256, D3 = 128;
constexpr int NROWS = 16384;
constexpr int MBLK = 64;            // batch rows per block
constexpr int NBLK = NROWS / MBLK;  // 256 blocks == #CUs
constexpr int KITERS = 16;
constexpr float ETA = 0.1f;

// packed-weight element offsets (fp16 elements) inside d_ws
constexpr int OFF_WF0 = 0;                  // fwd W0: K=256, N=512
constexpr int OFF_WF1 = OFF_WF0 + D1 * D0;  // fwd W1: K=256, N=256
constexpr int OFF_WF2 = OFF_WF1 + D2 * D1;  // fwd W2: K=128, N=256
constexpr int OFF_WB0 = OFF_WF2 + D3 * D2;  // bwd W0^T: K=512, N=256
constexpr int OFF_WB1 = OFF_WB0 + D0 * D1;  // bwd W1^T: K=256, N=256
constexpr int OFF_WB2 = OFF_WB1 + D1 * D2;  // bwd W2^T: K=256, N=128
constexpr int PACK_ELEMS = OFF_WB2 + D2 * D3;  // 458752 elems = 896 KB fp16

// ---------------------------------------------------------------------------
// Repack weights into MFMA B-fragment order + cast x0 to fp16 (if ws fits).
// B-frag layout (16x16x32): lane l supplies B[kt*32 + (l>>4)*8 + j][nt*16 + (l&15)],
// j=0..7 contiguous -> pack index ((kt*NT + nt)*64 + l)*8 + j.
// ---------------------------------------------------------------------------
__global__ void repack_kernel(const float* __restrict__ W0, const float* __restrict__ W1,
                              const float* __restrict__ W2, const float* __restrict__ x0,
                              _Float16* __restrict__ pack, _Float16* __restrict__ x0h,
                              int do_x0) {
  int p = blockIdx.x * 256 + threadIdx.x;
  if (p < PACK_ELEMS) {
    const float* W; int Csrc, Nd, off; bool tr;
    if (p < OFF_WF1)      { W = W0; Csrc = D0; Nd = D0; off = OFF_WF0; tr = false; }
    else if (p < OFF_WF2) { W = W1; Csrc = D1; Nd = D1; off = OFF_WF1; tr = false; }
    else if (p < OFF_WB0) { W = W2; Csrc = D2; Nd = D2; off = OFF_WF2; tr = false; }
    else if (p < OFF_WB1) { W = W0; Csrc = D0; Nd = D1; off = OFF_WB0; tr = true;  }
    else if (p < OFF_WB2) { W = W1; Csrc = D1; Nd = D1; off = OFF_WB1; tr = true;  }
    else                  { W = W2; Csrc = D2; Nd = D3; off = OFF_WB2; tr = true;  }
    int local = p - off;
    int j  = local & 7;
    int l  = (local >> 3) & 63;
    int fr = local >> 9;
    int NT = Nd >> 4;
    int nt = fr % NT, kt = fr / NT;
    int k = kt * 32 + ((l >> 4) << 3) + j;
    int n = nt * 16 + (l & 15);
    float v = tr ? W[n * Csrc + k] : W[k * Csrc + n];
    pack[p] = (_Float16)v;
  } else if (do_x0) {
    int q = p - PACK_ELEMS;
    if (q < NROWS * D0) x0h[q] = (_Float16)x0[q];
  }
}

DEV_INLINE float fast_tanh(float x) {
  float e = __expf(2.f * x);                       // v_exp_f32
  return 1.f - 2.f * __builtin_amdgcn_rcpf(e + 1.f);
}

// ---------------------------------------------------------------------------
// Tiled matmul: acc(4 x CT tiles) += A(64 x KSTEPS*32) @ Bpack[ntBase..+CT).
// B-fragments flow through a depth-P register pipeline (compile-time indices
// only -> registers). A in LDS, fp16, row stride STRB bytes, XOR-swizzled by
// ((row&7)<<4).
// ---------------------------------------------------------------------------
template <int KSTEPS, int NTT, int CT, int STRB, int P>
DEV_INLINE void mm_tiles(const char* __restrict__ A, const _Float16* __restrict__ Bp,
                         int ntBase, int lane, floatx4* acc) {
  const int arow = lane & 15;
  const int aoff = (lane >> 4) << 4;  // byte offset of this lane's 16B k-chunk
  const _Float16* bbase = Bp + ((size_t)(ntBase)*64 + lane) * 8;
  half8 bq[P][CT];
#pragma unroll
  for (int s = 0; s < P; ++s)
    if (s < KSTEPS)
#pragma unroll
      for (int ct = 0; ct < CT; ++ct)
        bq[s][ct] = *(const half8*)(bbase + (s * NTT + ct) * 512);
#pragma unroll
  for (int k0 = 0; k0 < KSTEPS; ++k0) {
    half8 a[4];
#pragma unroll
    for (int rt = 0; rt < 4; ++rt) {
      int row = rt * 16 + arow;
      int byte = (row * STRB + k0 * 64 + aoff) ^ ((row & 7) << 4);
      a[rt] = *(const half8*)(A + byte);
    }
#pragma unroll
    for (int ct = 0; ct < CT; ++ct)
#pragma unroll
      for (int rt = 0; rt < 4; ++rt)
        acc[rt * CT + ct] =
            __builtin_amdgcn_mfma_f32_16x16x32_f16(a[rt], bq[k0 % P][ct], acc[rt * CT + ct], 0, 0, 0);
    if (k0 + P < KSTEPS)
#pragma unroll
      for (int ct = 0; ct < CT; ++ct)
        bq[k0 % P][ct] = *(const half8*)(bbase + ((k0 + P) * NTT + ct) * 512);
  }
}

// ---------------------------------------------------------------------------
// Persistent settling kernel. States live as fp16 in LDS; x3 keeps an fp32
// register master (output precision). No other persistent registers -> worst
// phase live set ~100 VGPR, provably under the 128 allocator budget that all
// previous rounds overflowed (scratch spill -> L2 thrash -> weight misses).
// LDS (160 KB):
//   AX1 [32K]: x1  [64][256] s512   AG0 [32K]: g0-half [64][256] s512
//   AQ  [32K]: x2  [64][256] s512   AG1 [32K]: g1 [64][256] s512
//   AR  [32K]: x3 [64][128] s256  aliased with  g2 [64][256] s512
// Per iter: ph1(+ep->AG1), {ph3h(2x CT=1, ep->AG0), B, ph4h, B} x2,
//           ph4ep->AX1, ph2, B, ep->AR, ph5, B, ep->AQ, ph6, B, ep->AR.
// Every C-cell is owned by exactly one thread -> fp16 RMW in LDS is race-free.
// ---------------------------------------------------------------------------
__global__ __launch_bounds__(512)
void settle_kernel(const float* __restrict__ x0,
                   const _Float16* __restrict__ x0h,
                   const _Float16* __restrict__ pack,
                   float* __restrict__ out) {
  extern __shared__ char lds[];
  char* AX1 = lds;
  char* AG0 = lds + 32768;
  char* AQ  = lds + 65536;
  char* AG1 = lds + 98304;
  char* AR  = lds + 131072;

  const int tid  = threadIdx.x;
  const int lane = tid & 63;
  const int wave = tid >> 6;
  const int row0 = blockIdx.x * MBLK;
  const int rsub = (lane >> 4) << 2;  // C/D layout: row = (lane>>4)*4 + i
  const int csub = lane & 15;         //             col = lane & 15

  // zero-init x2 (AQ, 32K) and x3 image (AR, first 16K)
  {
    floatx4 z = {0.f, 0.f, 0.f, 0.f};
    for (int i = tid; i < 2048; i += 512) ((floatx4*)AQ)[i] = z;
    for (int i = tid; i < 1024; i += 512) ((floatx4*)AR)[i] = z;
  }

  const floatx4 zf = {0.f, 0.f, 0.f, 0.f};
  floatx4 x3m[4];  // fp32 master of the output layer
#pragma unroll
  for (int i = 0; i < 4; ++i) x3m[i] = zf;

  const _Float16* Wf0 = pack + OFF_WF0;
  const _Float16* Wf1 = pack + OFF_WF1;
  const _Float16* Wf2 = pack + OFF_WF2;
  const _Float16* Wb0 = pack + OFF_WB0;
  const _Float16* Wb1 = pack + OFF_WB1;
  const _Float16* Wb2 = pack + OFF_WB2;

  // =================== iteration 0 shortcut ===================
  // all states zero: g0 = x0 (f'(0)=1); only dx1 = x0 @ W0^T is nonzero.
  {
    floatx4 dx1a[8];
#pragma unroll
    for (int i = 0; i < 8; ++i) dx1a[i] = zf;
    for (int h = 0; h < 2; ++h) {
      for (int idx = tid; idx < MBLK * 256; idx += 512) {
        int row = idx >> 8, colh = idx & 255;
        size_t gi = (size_t)(row0 + row) * D0 + h * 256 + colh;
        _Float16 v = x0h ? x0h[gi] : (_Float16)x0[gi];
        int byte = (row * 512 + colh * 2) ^ ((row & 7) << 4);
        *(_Float16*)(AG0 + byte) = v;
      }
      __syncthreads();  // publish g0 half
      mm_tiles<8, 16, 2, 512, 2>(AG0, Wb0 + h * 65536, wave * 2, lane, dx1a);
      __syncthreads();  // reads done -> AG0 reusable
    }
#pragma unroll
    for (int rt = 0; rt < 4; ++rt)
#pragma unroll
      for (int ct = 0; ct < 2; ++ct) {
        int col = (wave * 2 + ct) * 16 + csub;
#pragma unroll
        for (int i = 0; i < 4; ++i) {
          int row = rt * 16 + rsub + i;
          float dx = fminf(1.f, fmaxf(-1.f, dx1a[rt * 2 + ct][i]));
          int byte = (row * 512 + col * 2) ^ ((row & 7) << 4);
          *(_Float16*)(AX1 + byte) = (_Float16)(ETA * dx);
        }
      }
    __syncthreads();  // publish x1
  }

  // =================== iterations 1..15 ===================
  for (int it = 1; it < KITERS; ++it) {
    floatx4 dx1a[8];
    // ---- ph1: preact1 = x2 @ W1 (reads AQ); ep: e1, g1 -> AG1, dx1a = -e1
    {
#pragma unroll
      for (int i = 0; i < 8; ++i) dx1a[i] = zf;
      mm_tiles<8, 16, 2, 512, 2>(AQ, Wf1, wave * 2, lane, dx1a);
#pragma unroll
      for (int rt = 0; rt < 4; ++rt)
#pragma unroll
        for (int ct = 0; ct < 2; ++ct) {
          int col = (wave * 2 + ct) * 16 + csub;
#pragma unroll
          for (int i = 0; i < 4; ++i) {
            int row = rt * 16 + rsub + i;
            int sb = (row * 512 + col * 2) ^ ((row & 7) << 4);
            float t = fast_tanh(dx1a[rt * 2 + ct][i]);
            float x1o = (float)*(const _Float16*)(AX1 + sb);
            float e = x1o - t;
            *(_Float16*)(AG1 + sb) = (_Float16)(e * (1.f - t * t));
            dx1a[rt * 2 + ct][i] = -e;
          }
        }
    }
    // ---- ph3/ph4 interleaved over the two K/N=256 halves of g0
    for (int h = 0; h < 2; ++h) {
      // ph3 half: preact0 cols h*256.. ; g0h -> AG0 (two CT=1 sub-passes)
#pragma unroll
      for (int c = 0; c < 2; ++c) {
        floatx4 acc[4];
#pragma unroll
        for (int i = 0; i < 4; ++i) acc[i] = zf;
        mm_tiles<8, 32, 1, 512, 2>(AX1, Wf0, h * 16 + wave * 2 + c, lane, acc);
        int colh = (wave * 2 + c) * 16 + csub;
#pragma unroll
        for (int rt = 0; rt < 4; ++rt)
#pragma unroll
          for (int i = 0; i < 4; ++i) {
            int row = rt * 16 + rsub + i;
            float t = fast_tanh(acc[rt][i]);
            size_t gi = (size_t)(row0 + row) * D0 + h * 256 + colh;
            float xv = x0h ? (float)x0h[gi] : x0[gi];
            float g = (xv - t) * (1.f - t * t);
            int byte = (row * 512 + colh * 2) ^ ((row & 7) << 4);
            *(_Float16*)(AG0 + byte) = (_Float16)g;
          }
      }
      __syncthreads();  // g0h published
      mm_tiles<8, 16, 2, 512, 2>(AG0, Wb0 + h * 65536, wave * 2, lane, dx1a);
      __syncthreads();  // ph4 half reads done -> AG0 reusable / AX1 writable
    }
    // ---- ph4 epilogue: x1 += eta*clip(dx1a)  (RMW own cells of AX1)
#pragma unroll
    for (int rt = 0; rt < 4; ++rt)
#pragma unroll
      for (int ct = 0; ct < 2; ++ct) {
        int col = (wave * 2 + ct) * 16 + csub;
#pragma unroll
        for (int i = 0; i < 4; ++i) {
          int row = rt * 16 + rsub + i;
          int sb = (row * 512 + col * 2) ^ ((row & 7) << 4);
          float dx = fminf(1.f, fmaxf(-1.f, dx1a[rt * 2 + ct][i]));
          float x1o = (float)*(const _Float16*)(AX1 + sb);
          *(_Float16*)(AX1 + sb) = (_Float16)(x1o + ETA * dx);
        }
      }
    // ---- ph2: preact2 = x3 @ W2 (reads AR x3 image); B; ep: e2, g2 -> AR
    floatx4 dx2a[8];
    {
#pragma unroll
      for (int i = 0; i < 8; ++i) dx2a[i] = zf;
      mm_tiles<4, 16, 2, 256, 2>(AR, Wf2, wave * 2, lane, dx2a);
      __syncthreads();  // all x3-image reads done before g2 overwrites AR
#pragma unroll
      for (int rt = 0; rt < 4; ++rt)
#pragma unroll
        for (int ct = 0; ct < 2; ++ct) {
          int col = (wave * 2 + ct) * 16 + csub;
#pragma unroll
          for (int i = 0; i < 4; ++i) {
            int row = rt * 16 + rsub + i;
            int sb = (row * 512 + col * 2) ^ ((row & 7) << 4);
            float t = fast_tanh(dx2a[rt * 2 + ct][i]);
            float x2o = (float)*(const _Float16*)(AQ + sb);
            float e = x2o - t;
            *(_Float16*)(AR + sb) = (_Float16)(e * (1.f - t * t));
            dx2a[rt * 2 + ct][i] = -e;
          }
        }
    }
    // ---- ph5: dx2a += g1 @ W1^T (reads AG1); B; ep: x2 RMW in AQ
    {
      mm_tiles<8, 16, 2, 512, 2>(AG1, Wb1, wave * 2, lane, dx2a);
      __syncthreads();  // covers ph2-ep AQ reads vs writes below; AG1 reads done
#pragma unroll
      for (int rt = 0; rt < 4; ++rt)
#pragma unroll
        for (int ct = 0; ct < 2; ++ct) {
          int col = (wave * 2 + ct) * 16 + csub;
#pragma unroll
          for (int i = 0; i < 4; ++i) {
            int row = rt * 16 + rsub + i;
            int sb = (row * 512 + col * 2) ^ ((row & 7) << 4);
            float dx = fminf(1.f, fmaxf(-1.f, dx2a[rt * 2 + ct][i]));
            float x2o = (float)*(const _Float16*)(AQ + sb);
            *(_Float16*)(AQ + sb) = (_Float16)(x2o + ETA * dx);
          }
        }
    }
    // ---- ph6: dx3 = g2 @ W2^T (reads AR g2); B; ep: x3m += ; x3 image -> AR
    {
      floatx4 acc6[4];
#pragma unroll
      for (int i = 0; i < 4; ++i) acc6[i] = zf;
      mm_tiles<8, 8, 1, 512, 2>(AR, Wb2, wave, lane, acc6);
      __syncthreads();  // all g2 reads done before x3 image overwrites AR
      int col = wave * 16 + csub;
#pragma unroll
      for (int rt = 0; rt < 4; ++rt)
#pragma unroll
        for (int i = 0; i < 4; ++i) {
          int row = rt * 16 + rsub + i;
          float dx = fminf(1.f, fmaxf(-1.f, acc6[rt][i]));
          float nv = x3m[rt][i] + ETA * dx;
          x3m[rt][i] = nv;
          int byte = (row * 256 + col * 2) ^ ((row & 7) << 4);
          *(_Float16*)(AR + byte) = (_Float16)nv;
        }
    }
  }

  // write settled x3 (fp32 master)
  {
    int col = wave * 16 + csub;
#pragma unroll
    for (int rt = 0; rt < 4; ++rt)
#pragma unroll
      for (int i = 0; i < 4; ++i) {
        int row = rt * 16 + rsub + i;
        out[(size_t)(row0 + row) * D3 + col] = x3m[rt][i];
      }
  }
}

extern "C" void kernel_launch(void* const* d_in, const int* in_sizes, int n_in,
                              void* d_out, int out_size, void* d_ws, size_t ws_size,
                              hipStream_t stream) {
  const float* x0 = (const float*)d_in[0];
  const float* W0 = (const float*)d_in[1];
  const float* W1 = (const float*)d_in[2];
  const float* W2 = (const float*)d_in[3];
  float* out = (float*)d_out;

  _Float16* pack = (_Float16*)d_ws;
  const size_t pack_bytes = (size_t)PACK_ELEMS * 2;
  const size_t x0h_bytes = (size_t)NROWS * D0 * 2;
  int do_x0 = (ws_size >= pack_bytes + x0h_bytes) ? 1 : 0;
  _Float16* x0h = do_x0 ? (_Float16*)((char*)d_ws + pack_bytes) : nullptr;

  int total = PACK_ELEMS + (do_x0 ? NROWS * D0 : 0);
  repack_kernel<<<(total + 255) / 256, 256, 0, stream>>>(W0, W1, W2, x0, pack, x0h, do_x0);

  (void)hipFuncSetAttribute(reinterpret_cast<const void*>(settle_kernel),
                            hipFuncAttributeMaxDynamicSharedMemorySize, 163840);
  settle_kernel<<<NBLK, 512, 163840, stream>>>(x0, x0h, pack, out);
}

// Round 9
// 1415.821 us; speedup vs baseline: 1.2416x; 1.1115x over previous
//
#include <hip/hip_runtime.h>

typedef _Float16 half8 __attribute__((ext_vector_type(8)));
typedef float floatx4 __attribute__((ext_vector_type(4)));

#define DEV_INLINE __device__ __forceinline__

constexpr int D0 = 512, D1 = 256, D2 = 256, D3 = 128;
constexpr int NROWS = 16384;
constexpr int MBLK = 64;            // batch rows per block
constexpr int NBLK = NROWS / MBLK;  // 256 blocks == #CUs
constexpr int KITERS = 16;
constexpr float ETA = 0.1f;

// packed-weight element offsets (fp16 elements) inside d_ws
constexpr int OFF_WF0 = 0;                  // fwd W0: K=256, N=512
constexpr int OFF_WF1 = OFF_WF0 + D1 * D0;  // fwd W1: K=256, N=256
constexpr int OFF_WF2 = OFF_WF1 + D2 * D1;  // fwd W2: K=128, N=256
constexpr int OFF_WB0 = OFF_WF2 + D3 * D2;  // bwd W0^T: K=512, N=256
constexpr int OFF_WB1 = OFF_WB0 + D0 * D1;  // bwd W1^T: K=256, N=256
constexpr int OFF_WB2 = OFF_WB1 + D1 * D2;  // bwd W2^T: K=256, N=128
constexpr int PACK_ELEMS = OFF_WB2 + D2 * D3;  // 458752 elems = 896 KB fp16

// ---------------------------------------------------------------------------
// Repack weights into MFMA B-fragment order.
// B-frag layout (16x16x32): lane l supplies B[kt*32 + (l>>4)*8 + j][nt*16 + (l&15)],
// j=0..7 contiguous -> pack index ((kt*NT + nt)*64 + l)*8 + j.
// ---------------------------------------------------------------------------
__global__ void repack_kernel(const float* __restrict__ W0, const float* __restrict__ W1,
                              const float* __restrict__ W2, _Float16* __restrict__ pack) {
  int p = blockIdx.x * 256 + threadIdx.x;
  if (p >= PACK_ELEMS) return;
  const float* W; int Csrc, Nd, off; bool tr;
  if (p < OFF_WF1)      { W = W0; Csrc = D0; Nd = D0; off = OFF_WF0; tr = false; }
  else if (p < OFF_WF2) { W = W1; Csrc = D1; Nd = D1; off = OFF_WF1; tr = false; }
  else if (p < OFF_WB0) { W = W2; Csrc = D2; Nd = D2; off = OFF_WF2; tr = false; }
  else if (p < OFF_WB1) { W = W0; Csrc = D0; Nd = D1; off = OFF_WB0; tr = true;  }
  else if (p < OFF_WB2) { W = W1; Csrc = D1; Nd = D1; off = OFF_WB1; tr = true;  }
  else                  { W = W2; Csrc = D2; Nd = D3; off = OFF_WB2; tr = true;  }
  int local = p - off;
  int j  = local & 7;
  int l  = (local >> 3) & 63;
  int fr = local >> 9;
  int NT = Nd >> 4;
  int nt = fr % NT, kt = fr / NT;
  int k = kt * 32 + ((l >> 4) << 3) + j;
  int n = nt * 16 + (l & 15);
  float v = tr ? W[n * Csrc + k] : W[k * Csrc + n];
  pack[p] = (_Float16)v;
}

DEV_INLINE float fast_tanh(float x) {
  float e = __expf(2.f * x);                       // v_exp_f32
  return 1.f - 2.f * __builtin_amdgcn_rcpf(e + 1.f);
}

// Async global->LDS DMA, 16B/lane (global_load_lds_dwordx4). LDS dest is
// wave-uniform base; HW writes lane i at base + i*16. Source is per-lane.
DEV_INLINE void gl_lds16(const _Float16* g, char* l) {
  __builtin_amdgcn_global_load_lds(
      (const __attribute__((address_space(1))) unsigned int*)g,
      (__attribute__((address_space(3))) unsigned int*)l, 16, 0, 0);
}

// ---------------------------------------------------------------------------
// Staged matmul: acc[rt*ASd] += A(64 x KSTEPS*32) @ Bpack[tile nt], where the
// B-tiles stream through a WAVE-PRIVATE 2x1KB LDS slot via global_load_lds,
// double-buffered with counted s_waitcnt vmcnt(1) (no cross-wave barriers,
// no VGPR transit). Only VMEM ops in this loop are the staging DMAs, so the
// vmcnt accounting is exact. A in LDS, fp16, row stride STRB bytes,
// XOR-swizzled by ((row&7)<<4).
// ---------------------------------------------------------------------------
template <int KSTEPS, int NTT, int STRB, int ASd>
DEV_INLINE void mm_staged(const char* __restrict__ A, const _Float16* __restrict__ Bp,
                          int nt, int lane, char* __restrict__ wslot, floatx4* acc) {
  const int arow = lane & 15;
  const int aoff = (lane >> 4) << 4;  // byte offset of this lane's 16B k-chunk
  const _Float16* bsrc = Bp + ((size_t)nt * 64 + lane) * 8;
  gl_lds16(bsrc, wslot);  // prologue: k0=0 -> slot 0
#pragma unroll
  for (int k0 = 0; k0 < KSTEPS; ++k0) {
    if (k0 + 1 < KSTEPS) {
      gl_lds16(bsrc + (size_t)(k0 + 1) * NTT * 512, wslot + ((k0 + 1) & 1) * 1024);
      asm volatile("s_waitcnt vmcnt(1)" ::: "memory");  // oldest (k0) retired
    } else {
      asm volatile("s_waitcnt vmcnt(0)" ::: "memory");
    }
    __builtin_amdgcn_sched_barrier(0);  // rule #18: pin ds_read below waitcnt
    const half8 b = *(const half8*)(wslot + (k0 & 1) * 1024 + lane * 16);
#pragma unroll
    for (int rt = 0; rt < 4; ++rt) {
      int row = rt * 16 + arow;
      int byte = (row * STRB + k0 * 64 + aoff) ^ ((row & 7) << 4);
      half8 a = *(const half8*)(A + byte);
      acc[rt * ASd] = __builtin_amdgcn_mfma_f32_16x16x32_f16(a, b, acc[rt * ASd], 0, 0, 0);
    }
  }
}

// ---------------------------------------------------------------------------
// Persistent settling kernel. States fp16 in LDS; x3 fp32 register master;
// x0 tile in registers (x0r). LDS (160 KB exactly):
//   AX1 [32K]@0     : x1 [64][256] s512
//   AG0 [32K]@32K   : g0-half [64][256] s512, then g2 [64][256] s512
//   AQ  [32K]@64K   : x2 [64][256] s512
//   AG1 [32K]@96K   : g1 [64][256] s512
//   AR  [16K]@128K  : x3 image [64][128] s256
//   WSL [16K]@144K  : 8 waves x 2 slots x 1KB B-staging
// Per iter: P1(+ep g1->AG1), {P3h(2xCT1, ep->AG0), B, P4h, B} x2, P4ep,
//           [B6], P2(2xCT1, ep: e2, g2->AG0), P5a(g1@W1^T), P5ep, [B7],
//           P6, [B9], P6ep. 6 barriers/iter; staging needs none (wave-private).
// ---------------------------------------------------------------------------
__global__ __launch_bounds__(512)
void settle_kernel(const float* __restrict__ x0,
                   const _Float16* __restrict__ pack,
                   float* __restrict__ out) {
  extern __shared__ char lds[];
  char* AX1 = lds;
  char* AG0 = lds + 32768;
  char* AQ  = lds + 65536;
  char* AG1 = lds + 98304;
  char* AR  = lds + 131072;
  char* WSL = lds + 147456;

  const int tid  = threadIdx.x;
  const int lane = tid & 63;
  const int wave = tid >> 6;
  const int row0 = blockIdx.x * MBLK;
  const int rsub = (lane >> 4) << 2;  // C/D layout: row = (lane>>4)*4 + i
  const int csub = lane & 15;         //             col = lane & 15
  char* ws = WSL + wave * 2048;       // this wave's private staging slot pair

  // ---- preload this block's x0 tile into registers (fp16), C-cell ownership
  // li = ((h*2 + c)*4 + rt)*4 + i  <->  row = rt*16+rsub+i,
  //                                     col = h*256 + (wave*2+c)*16 + csub
  half8 x0r[8];
#pragma unroll
  for (int h = 0; h < 2; ++h)
#pragma unroll
    for (int c = 0; c < 2; ++c)
#pragma unroll
      for (int rt = 0; rt < 4; ++rt)
#pragma unroll
        for (int i = 0; i < 4; ++i) {
          int row = rt * 16 + rsub + i;
          int col = h * 256 + (wave * 2 + c) * 16 + csub;
          float v = x0[(size_t)(row0 + row) * D0 + col];
          int li = ((h * 2 + c) * 4 + rt) * 4 + i;
          x0r[li >> 3][li & 7] = (_Float16)v;
        }

  // zero-init x2 (AQ, 32K) and x3 image (AR, 16K)
  {
    floatx4 z = {0.f, 0.f, 0.f, 0.f};
    for (int i = tid; i < 2048; i += 512) ((floatx4*)AQ)[i] = z;
    for (int i = tid; i < 1024; i += 512) ((floatx4*)AR)[i] = z;
  }

  const floatx4 zf = {0.f, 0.f, 0.f, 0.f};
  floatx4 x3m[4];  // fp32 master of the output layer
#pragma unroll
  for (int i = 0; i < 4; ++i) x3m[i] = zf;

  const _Float16* Wf0 = pack + OFF_WF0;
  const _Float16* Wf1 = pack + OFF_WF1;
  const _Float16* Wf2 = pack + OFF_WF2;
  const _Float16* Wb0 = pack + OFF_WB0;
  const _Float16* Wb1 = pack + OFF_WB1;
  const _Float16* Wb2 = pack + OFF_WB2;

  // =================== iteration 0 shortcut ===================
  // all states zero: g0 = x0 (f'(0)=1); only dx1 = x0 @ W0^T is nonzero.
  {
    floatx4 dx1a[8];
#pragma unroll
    for (int i = 0; i < 8; ++i) dx1a[i] = zf;
#pragma unroll
    for (int h = 0; h < 2; ++h) {
      // stage g0-half = x0-half from registers (consumes x0r -> drains x0 loads)
#pragma unroll
      for (int c = 0; c < 2; ++c)
#pragma unroll
        for (int rt = 0; rt < 4; ++rt)
#pragma unroll
          for (int i = 0; i < 4; ++i) {
            int row = rt * 16 + rsub + i;
            int colh = (wave * 2 + c) * 16 + csub;
            int li = ((h * 2 + c) * 4 + rt) * 4 + i;
            int byte = (row * 512 + colh * 2) ^ ((row & 7) << 4);
            *(_Float16*)(AG0 + byte) = x0r[li >> 3][li & 7];
          }
      __syncthreads();  // publish g0 half (also drains all VMEM: clean vmcnt)
#pragma unroll
      for (int ct = 0; ct < 2; ++ct)
        mm_staged<8, 16, 512, 2>(AG0, Wb0 + h * 65536, wave * 2 + ct, lane, ws, &dx1a[ct]);
      __syncthreads();  // reads done -> AG0 reusable
    }
#pragma unroll
    for (int rt = 0; rt < 4; ++rt)
#pragma unroll
      for (int ct = 0; ct < 2; ++ct) {
        int col = (wave * 2 + ct) * 16 + csub;
#pragma unroll
        for (int i = 0; i < 4; ++i) {
          int row = rt * 16 + rsub + i;
          float dx = fminf(1.f, fmaxf(-1.f, dx1a[rt * 2 + ct][i]));
          int byte = (row * 512 + col * 2) ^ ((row & 7) << 4);
          *(_Float16*)(AX1 + byte) = (_Float16)(ETA * dx);
        }
      }
    __syncthreads();  // publish x1
  }

  // =================== iterations 1..15 ===================
  for (int it = 1; it < KITERS; ++it) {
    floatx4 dx1a[8];
    // ---- P1: preact1 = x2 @ W1 (reads AQ); ep: e1, g1 -> AG1, dx1a = -e1
    {
#pragma unroll
      for (int i = 0; i < 8; ++i) dx1a[i] = zf;
#pragma unroll
      for (int ct = 0; ct < 2; ++ct)
        mm_staged<8, 16, 512, 2>(AQ, Wf1, wave * 2 + ct, lane, ws, &dx1a[ct]);
#pragma unroll
      for (int rt = 0; rt < 4; ++rt)
#pragma unroll
        for (int ct = 0; ct < 2; ++ct) {
          int col = (wave * 2 + ct) * 16 + csub;
#pragma unroll
          for (int i = 0; i < 4; ++i) {
            int row = rt * 16 + rsub + i;
            int sb = (row * 512 + col * 2) ^ ((row & 7) << 4);
            float t = fast_tanh(dx1a[rt * 2 + ct][i]);
            float x1o = (float)*(const _Float16*)(AX1 + sb);
            float e = x1o - t;
            *(_Float16*)(AG1 + sb) = (_Float16)(e * (1.f - t * t));
            dx1a[rt * 2 + ct][i] = -e;
          }
        }
    }
    // ---- P3/P4 interleaved over the two K/N=256 halves of g0
#pragma unroll
    for (int h = 0; h < 2; ++h) {
#pragma unroll
      for (int c = 0; c < 2; ++c) {
        floatx4 acc[4];
#pragma unroll
        for (int i = 0; i < 4; ++i) acc[i] = zf;
        mm_staged<8, 32, 512, 1>(AX1, Wf0, h * 16 + wave * 2 + c, lane, ws, acc);
        int colh = (wave * 2 + c) * 16 + csub;
#pragma unroll
        for (int rt = 0; rt < 4; ++rt)
#pragma unroll
          for (int i = 0; i < 4; ++i) {
            int row = rt * 16 + rsub + i;
            int li = ((h * 2 + c) * 4 + rt) * 4 + i;
            float t = fast_tanh(acc[rt][i]);
            float xv = (float)x0r[li >> 3][li & 7];
            float g = (xv - t) * (1.f - t * t);
            int byte = (row * 512 + colh * 2) ^ ((row & 7) << 4);
            *(_Float16*)(AG0 + byte) = (_Float16)g;
          }
      }
      __syncthreads();  // B3/B5: g0h published
#pragma unroll
      for (int ct = 0; ct < 2; ++ct)
        mm_staged<8, 16, 512, 2>(AG0, Wb0 + h * 65536, wave * 2 + ct, lane, ws, &dx1a[ct]);
      __syncthreads();  // B4/B6a: P4h reads done -> AG0 reusable
    }
    // ---- P4 epilogue: x1 += eta*clip(dx1a)  (RMW own cells of AX1)
#pragma unroll
    for (int rt = 0; rt < 4; ++rt)
#pragma unroll
      for (int ct = 0; ct < 2; ++ct) {
        int col = (wave * 2 + ct) * 16 + csub;
#pragma unroll
        for (int i = 0; i < 4; ++i) {
          int row = rt * 16 + rsub + i;
          int sb = (row * 512 + col * 2) ^ ((row & 7) << 4);
          float dx = fminf(1.f, fmaxf(-1.f, dx1a[rt * 2 + ct][i]));
          float x1o = (float)*(const _Float16*)(AX1 + sb);
          *(_Float16*)(AX1 + sb) = (_Float16)(x1o + ETA * dx);
        }
      }
    // ---- P2: preact2 = x3 @ W2 (reads AR x3 image); ep: e2, g2 -> AG0,
    //          dx2a = -e2   (AG0 free: last reads barrier'd above)
    floatx4 dx2a[8];
    {
      floatx4 p2[8];
#pragma unroll
      for (int i = 0; i < 8; ++i) p2[i] = zf;
#pragma unroll
      for (int ct = 0; ct < 2; ++ct)
        mm_staged<4, 16, 256, 2>(AR, Wf2, wave * 2 + ct, lane, ws, &p2[ct]);
#pragma unroll
      for (int rt = 0; rt < 4; ++rt)
#pragma unroll
        for (int ct = 0; ct < 2; ++ct) {
          int col = (wave * 2 + ct) * 16 + csub;
#pragma unroll
          for (int i = 0; i < 4; ++i) {
            int row = rt * 16 + rsub + i;
            int sb = (row * 512 + col * 2) ^ ((row & 7) << 4);
            float t = fast_tanh(p2[rt * 2 + ct][i]);
            float x2o = (float)*(const _Float16*)(AQ + sb);
            float e = x2o - t;
            *(_Float16*)(AG0 + sb) = (_Float16)(e * (1.f - t * t));
            dx2a[rt * 2 + ct][i] = -e;
          }
        }
    }
    // ---- P5a: dx2a += g1 @ W1^T (reads AG1); P5ep: x2 RMW in AQ
    {
#pragma unroll
      for (int ct = 0; ct < 2; ++ct)
        mm_staged<8, 16, 512, 2>(AG1, Wb1, wave * 2 + ct, lane, ws, &dx2a[ct]);
#pragma unroll
      for (int rt = 0; rt < 4; ++rt)
#pragma unroll
        for (int ct = 0; ct < 2; ++ct) {
          int col = (wave * 2 + ct) * 16 + csub;
#pragma unroll
          for (int i = 0; i < 4; ++i) {
            int row = rt * 16 + rsub + i;
            int sb = (row * 512 + col * 2) ^ ((row & 7) << 4);
            float dx = fminf(1.f, fmaxf(-1.f, dx2a[rt * 2 + ct][i]));
            float x2o = (float)*(const _Float16*)(AQ + sb);
            *(_Float16*)(AQ + sb) = (_Float16)(x2o + ETA * dx);
          }
        }
    }
    __syncthreads();  // B7: publish g2 (AG0); AG1 reads done
    // ---- P6: dx3 = g2 @ W2^T (reads AG0); B9; ep: x3m +=; x3 image -> AR
    {
      floatx4 acc6[4];
#pragma unroll
      for (int i = 0; i < 4; ++i) acc6[i] = zf;
      mm_staged<8, 8, 512, 1>(AG0, Wb2, wave, lane, ws, acc6);
      __syncthreads();  // B9: all g2/AG1 reads done before next-iter overwrites
      int col = wave * 16 + csub;
#pragma unroll
      for (int rt = 0; rt < 4; ++rt)
#pragma unroll
        for (int i = 0; i < 4; ++i) {
          int row = rt * 16 + rsub + i;
          float dx = fminf(1.f, fmaxf(-1.f, acc6[rt][i]));
          float nv = x3m[rt][i] + ETA * dx;
          x3m[rt][i] = nv;
          int byte = (row * 256 + col * 2) ^ ((row & 7) << 4);
          *(_Float16*)(AR + byte) = (_Float16)nv;
        }
    }
  }

  // write settled x3 (fp32 master)
  {
    int col = wave * 16 + csub;
#pragma unroll
    for (int rt = 0; rt < 4; ++rt)
#pragma unroll
      for (int i = 0; i < 4; ++i) {
        int row = rt * 16 + rsub + i;
        out[(size_t)(row0 + row) * D3 + col] = x3m[rt][i];
      }
  }
}

extern "C" void kernel_launch(void* const* d_in, const int* in_sizes, int n_in,
                              void* d_out, int out_size, void* d_ws, size_t ws_size,
                              hipStream_t stream) {
  const float* x0 = (const float*)d_in[0];
  const float* W0 = (const float*)d_in[1];
  const float* W1 = (const float*)d_in[2];
  const float* W2 = (const float*)d_in[3];
  float* out = (float*)d_out;

  _Float16* pack = (_Float16*)d_ws;
  repack_kernel<<<(PACK_ELEMS + 255) / 256, 256, 0, stream>>>(W0, W1, W2, pack);

  (void)hipFuncSetAttribute(reinterpret_cast<const void*>(settle_kernel),
                            hipFuncAttributeMaxDynamicSharedMemorySize, 163840);
  settle_kernel<<<NBLK, 512, 163840, stream>>>(x0, pack, out);
}